// Round 2
// baseline (395.496 us; speedup 1.0000x reference)
//
#include <hip/hip_runtime.h>

#define NN 50000
#define NE 800000
#define KF 256
#define MF 64

// ---------------- GEMM: hw[i][j] = (sum_k h[i][k]*W[k][j]) * norm[i] -------
// Block=512 (8 waves), each wave does 8 rows x 64 cols; W [k][col] in LDS
// (64 KB -> 2 blocks/CU, launch_bounds(512,4) caps VGPR at 128).
__global__ __launch_bounds__(512, 4) void gemm_norm(
    const float* __restrict__ h, const float* __restrict__ W,
    const float* __restrict__ norm, float* __restrict__ hw) {
  __shared__ float ws[KF * MF];  // 64 KB
  const int t = threadIdx.x;
  {
    const float4* W4 = (const float4*)W;
    float4* s4 = (float4*)ws;
#pragma unroll
    for (int i = 0; i < 8; ++i) s4[i * 512 + t] = W4[i * 512 + t];
  }
  __syncthreads();

  const int col = t & 63;
  const int wv = __builtin_amdgcn_readfirstlane(t >> 6);  // 0..7, uniform
  int row0 = blockIdx.x * 64 + wv * 8;
  if (row0 + 8 > NN) row0 = NN - 8;  // tail waves recompute rows (same values)
  const float4* h4 = (const float4*)(h + (size_t)row0 * KF);

  float acc[8] = {0.f, 0.f, 0.f, 0.f, 0.f, 0.f, 0.f, 0.f};
#pragma unroll 2
  for (int k4 = 0; k4 < KF / 4; ++k4) {
    const float* wp = ws + k4 * 4 * MF + col;  // stride-1 across lanes: no conflict
    const float w0 = wp[0], w1 = wp[MF], w2 = wp[2 * MF], w3 = wp[3 * MF];
#pragma unroll
    for (int r = 0; r < 8; ++r) {
      float4 a = h4[r * (KF / 4) + k4];  // wave-uniform broadcast load
      acc[r] += a.x * w0 + a.y * w1 + a.z * w2 + a.w * w3;
    }
  }
#pragma unroll
  for (int r = 0; r < 8; ++r)
    hw[(size_t)(row0 + r) * MF + col] = acc[r] * norm[row0 + r];
}

// ---------------- CSR build ------------------------------------------------
__global__ __launch_bounds__(256) void count_edges(
    const int* __restrict__ dst, int* __restrict__ cnt) {
  const int e = blockIdx.x * 256 + threadIdx.x;
  if (e < NE) atomicAdd(&cnt[dst[e]], 1);
}

#define SCAN_T 1024
#define CHUNK 49  // ceil(50000/1024)
// Single-block exclusive scan. cnt and cursor may alias (read-before-write
// per element, one owner thread each).
__global__ __launch_bounds__(SCAN_T) void scan_offsets(
    const int* __restrict__ cnt, int* __restrict__ offs, int* __restrict__ cursor) {
  __shared__ int part[SCAN_T];
  const int t = threadIdx.x;
  const int base = t * CHUNK;
  int sum = 0;
  for (int i = 0; i < CHUNK; ++i) {
    const int idx = base + i;
    if (idx < NN) sum += cnt[idx];
  }
  part[t] = sum;
  __syncthreads();
  for (int off = 1; off < SCAN_T; off <<= 1) {
    const int add = (t >= off) ? part[t - off] : 0;
    __syncthreads();
    part[t] += add;
    __syncthreads();
  }
  int run = part[t] - sum;  // exclusive prefix of this thread's chunk
  for (int i = 0; i < CHUNK; ++i) {
    const int idx = base + i;
    if (idx < NN) {
      const int v = cnt[idx];  // read BEFORE cursor write (may alias)
      offs[idx] = run;
      cursor[idx] = run;
      run += v;
    }
  }
  if (t == 0) offs[NN] = part[SCAN_T - 1];
}

__global__ __launch_bounds__(256) void fill_edges(
    const int* __restrict__ src, const int* __restrict__ dst,
    int* __restrict__ cursor, int* __restrict__ eidx) {
  const int e = blockIdx.x * 256 + threadIdx.x;
  if (e < NE) {
    const int p = atomicAdd(&cursor[dst[e]], 1);
    eidx[p] = src[e];
  }
}

// ---------------- Gather-reduce + epilogue ---------------------------------
// One wave per node, lane = feature column. Deterministic fp32 sum order.
__global__ __launch_bounds__(256) void gather_finalize(
    const int* __restrict__ offs, const int* __restrict__ eidx,
    const float* __restrict__ hw, const float* __restrict__ norm,
    const float* __restrict__ bias, float* __restrict__ out) {
  const int t = threadIdx.x;
  const int lane = t & 63;
  const int v = blockIdx.x * 4 + (t >> 6);
  if (v >= NN) return;
  const int beg = __builtin_amdgcn_readfirstlane(offs[v]);
  const int end = __builtin_amdgcn_readfirstlane(offs[v + 1]);
  float acc = 0.f;
  int i = beg;
  for (; i + 2 <= end; i += 2) {  // 2 hw-row loads in flight
    const int s0 = eidx[i];
    const int s1 = eidx[i + 1];
    const float x0 = hw[(size_t)s0 * MF + lane];
    const float x1 = hw[(size_t)s1 * MF + lane];
    acc += x0;
    acc += x1;
  }
  if (i < end) acc += hw[(size_t)eidx[i] * MF + lane];
  const float o = acc * norm[v] + bias[lane];
  out[(size_t)v * MF + lane] = fmaxf(o, 0.f);
}

extern "C" void kernel_launch(void* const* d_in, const int* in_sizes, int n_in,
                              void* d_out, int out_size, void* d_ws, size_t ws_size,
                              hipStream_t stream) {
  const float* h = (const float*)d_in[0];
  const float* norm = (const float*)d_in[1];
  const float* W = (const float*)d_in[2];
  const float* bias = (const float*)d_in[3];
  const int* src = (const int*)d_in[4];
  const int* dst = (const int*)d_in[5];
  float* out = (float*)d_out;

  // Workspace layout
  float* hw = (float*)d_ws;                        // NN*MF floats = 12.8 MB
  int* offs = (int*)(hw + (size_t)NN * MF);        // NN+1 ints (+3 pad)
  int* cnt_cursor = offs + NN + 4;                 // NN ints (counts, then cursor)
  int* eidx = cnt_cursor + NN;                     // NE ints
  const size_t need = ((size_t)NN * MF + (NN + 4) + NN + NE) * 4;
  if (ws_size < need) return;

  hipMemsetAsync(cnt_cursor, 0, (size_t)NN * sizeof(int), stream);

  gemm_norm<<<(NN + 63) / 64, 512, 0, stream>>>(h, W, norm, hw);     // 782 blocks
  count_edges<<<(NE + 255) / 256, 256, 0, stream>>>(dst, cnt_cursor);
  scan_offsets<<<1, SCAN_T, 0, stream>>>(cnt_cursor, offs, cnt_cursor);
  fill_edges<<<(NE + 255) / 256, 256, 0, stream>>>(src, dst, cnt_cursor, eidx);
  gather_finalize<<<(NN + 3) / 4, 256, 0, stream>>>(offs, eidx, hw, norm, bias, out);
}

// Round 3
// 236.699 us; speedup vs baseline: 1.6709x; 1.6709x over previous
//
#include <hip/hip_runtime.h>

#define NN 50000
#define NE 800000
#define KF 256
#define MF 64
#define PKU 264  // LDS row pitch in ushort units (256 + 8 pad = 528 B)

typedef __attribute__((ext_vector_type(8))) short short8;
typedef __attribute__((ext_vector_type(4))) float f32x4;
typedef __attribute__((ext_vector_type(4))) unsigned short us4;

static __device__ __forceinline__ unsigned short f2bf(float x) {
  unsigned int u = __float_as_uint(x);
  u += 0x7FFF + ((u >> 16) & 1);  // round-nearest-even
  return (unsigned short)(u >> 16);
}

// ---------------- MFMA bf16 GEMM: hw[i][j] = (h@W)[i][j] * norm[i] ---------
// Block = 256 (4 waves), 64 rows/block, full N=64. Wave w: rows [w*16,w*16+16),
// 4 n-tiles of 16. fp32->bf16 conversion fused into LDS staging.
__global__ __launch_bounds__(256, 2) void gemm_mfma(
    const float* __restrict__ h, const float* __restrict__ W,
    const float* __restrict__ norm, float* __restrict__ hw) {
  __shared__ unsigned short la[64 * PKU];  // A tile [m][k] bf16
  __shared__ unsigned short lb[64 * PKU];  // B^T    [n][k] bf16
  const int t = threadIdx.x;
  const int row0 = blockIdx.x * 64;

  // Stage W^T -> lb (coalesced fp32 reads, 4 k per thread)
#pragma unroll
  for (int it = 0; it < 16; ++it) {
    const int cid = it * 256 + t;
    const int n = cid & 63;
    const int kc = cid >> 6;  // 0..63 (k chunk of 4)
    const float w0 = W[(kc * 4 + 0) * MF + n];
    const float w1 = W[(kc * 4 + 1) * MF + n];
    const float w2 = W[(kc * 4 + 2) * MF + n];
    const float w3 = W[(kc * 4 + 3) * MF + n];
    us4 p = {f2bf(w0), f2bf(w1), f2bf(w2), f2bf(w3)};
    *(us4*)&lb[n * PKU + kc * 4] = p;
  }
  // Stage h tile -> la (coalesced float4 reads)
  {
    const float4* h4 = (const float4*)h;
#pragma unroll
    for (int it = 0; it < 16; ++it) {
      const int cid = it * 256 + t;
      const int r = cid >> 6;   // 0..63
      const int kc = cid & 63;  // float4 index
      const int gr = row0 + r;
      float4 a = make_float4(0.f, 0.f, 0.f, 0.f);
      if (gr < NN) a = h4[(size_t)gr * (KF / 4) + kc];
      us4 p = {f2bf(a.x), f2bf(a.y), f2bf(a.z), f2bf(a.w)};
      *(us4*)&la[r * PKU + kc * 4] = p;
    }
  }
  __syncthreads();

  const int lane = t & 63;
  const int wv = t >> 6;        // 0..3
  const int m = lane & 15;      // row/col within 16-tile
  const int quad = lane >> 4;   // 0..3

  f32x4 acc[4];
#pragma unroll
  for (int i = 0; i < 4; ++i) acc[i] = (f32x4){0.f, 0.f, 0.f, 0.f};

  const unsigned short* pa = &la[(wv * 16 + m) * PKU + quad * 8];
  const unsigned short* pb = &lb[m * PKU + quad * 8];
#pragma unroll
  for (int k0 = 0; k0 < KF; k0 += 32) {
    const short8 af = *(const short8*)(pa + k0);
#pragma unroll
    for (int nt = 0; nt < 4; ++nt) {
      const short8 bf = *(const short8*)(pb + nt * 16 * PKU + k0);
      acc[nt] = __builtin_amdgcn_mfma_f32_16x16x32_bf16(af, bf, acc[nt], 0, 0, 0);
    }
  }

  // Epilogue: D row = quad*4 + reg, col = nt*16 + m
  const int gm0 = row0 + wv * 16 + quad * 4;
  float nrm[4];
#pragma unroll
  for (int r = 0; r < 4; ++r) nrm[r] = (gm0 + r < NN) ? norm[gm0 + r] : 0.f;
#pragma unroll
  for (int nt = 0; nt < 4; ++nt) {
#pragma unroll
    for (int r = 0; r < 4; ++r) {
      const int gm = gm0 + r;
      if (gm < NN) hw[(size_t)gm * MF + nt * 16 + m] = acc[nt][r] * nrm[r];
    }
  }
}

// ---------------- CSR build ------------------------------------------------
__global__ __launch_bounds__(256) void count_edges(
    const int* __restrict__ dst, int* __restrict__ cnt) {
  const int e = blockIdx.x * 256 + threadIdx.x;
  if (e < NE) atomicAdd(&cnt[dst[e]], 1);
}

#define SB 1024
#define NBLK 49  // ceil(50000/1024)

// Per-block Hillis-Steele scan, in-place: cnt[i] -> local exclusive scan.
__global__ __launch_bounds__(SB) void scan_local(
    int* __restrict__ cnt, int* __restrict__ bsum) {
  __shared__ int s[SB];
  const int t = threadIdx.x;
  const int i = blockIdx.x * SB + t;
  const int v = (i < NN) ? cnt[i] : 0;
  s[t] = v;
  __syncthreads();
  for (int off = 1; off < SB; off <<= 1) {
    const int a = (t >= off) ? s[t - off] : 0;
    __syncthreads();
    s[t] += a;
    __syncthreads();
  }
  if (i < NN) cnt[i] = s[t] - v;  // exclusive
  if (t == SB - 1) bsum[blockIdx.x] = s[t];
}

// One wave: exclusive scan of the 49 block sums.
__global__ __launch_bounds__(64) void scan_base(
    const int* __restrict__ bsum, int* __restrict__ base) {
  const int t = threadIdx.x;
  int v = (t < NBLK) ? bsum[t] : 0;
  const int orig = v;
  for (int off = 1; off < 64; off <<= 1) {
    const int u = __shfl_up(v, off, 64);
    if (t >= off) v += u;
  }
  if (t < NBLK) base[t] = v - orig;
}

__global__ __launch_bounds__(SB) void add_base(
    const int* __restrict__ cnt, const int* __restrict__ base,
    int* __restrict__ offs, int* __restrict__ cursor) {
  const int i = blockIdx.x * SB + threadIdx.x;
  if (i < NN) {
    const int o = cnt[i] + base[i >> 10];
    offs[i] = o;
    cursor[i] = o;
  }
  if (i == 0) offs[NN] = NE;  // total degree is always NE
}

__global__ __launch_bounds__(256) void fill_edges(
    const int* __restrict__ src, const int* __restrict__ dst,
    int* __restrict__ cursor, int* __restrict__ eidx) {
  const int e = blockIdx.x * 256 + threadIdx.x;
  if (e < NE) {
    const int p = atomicAdd(&cursor[dst[e]], 1);
    eidx[p] = src[e];
  }
}

// ---------------- Gather-reduce + epilogue ---------------------------------
// One wave per node, lane = feature column. Deterministic fp32 sum order.
__global__ __launch_bounds__(256) void gather_finalize(
    const int* __restrict__ offs, const int* __restrict__ eidx,
    const float* __restrict__ hw, const float* __restrict__ norm,
    const float* __restrict__ bias, float* __restrict__ out) {
  const int t = threadIdx.x;
  const int lane = t & 63;
  const int v = blockIdx.x * 4 + (t >> 6);
  if (v >= NN) return;
  const int beg = __builtin_amdgcn_readfirstlane(offs[v]);
  const int end = __builtin_amdgcn_readfirstlane(offs[v + 1]);
  float acc = 0.f;
  int i = beg;
  for (; i + 4 <= end; i += 4) {  // 4 row-loads in flight
    const int s0 = eidx[i], s1 = eidx[i + 1], s2 = eidx[i + 2], s3 = eidx[i + 3];
    const float x0 = hw[(size_t)s0 * MF + lane];
    const float x1 = hw[(size_t)s1 * MF + lane];
    const float x2 = hw[(size_t)s2 * MF + lane];
    const float x3 = hw[(size_t)s3 * MF + lane];
    acc += x0; acc += x1; acc += x2; acc += x3;
  }
  for (; i < end; ++i) acc += hw[(size_t)eidx[i] * MF + lane];
  const float o = acc * norm[v] + bias[lane];
  out[(size_t)v * MF + lane] = fmaxf(o, 0.f);
}

extern "C" void kernel_launch(void* const* d_in, const int* in_sizes, int n_in,
                              void* d_out, int out_size, void* d_ws, size_t ws_size,
                              hipStream_t stream) {
  const float* h = (const float*)d_in[0];
  const float* norm = (const float*)d_in[1];
  const float* W = (const float*)d_in[2];
  const float* bias = (const float*)d_in[3];
  const int* src = (const int*)d_in[4];
  const int* dst = (const int*)d_in[5];
  float* out = (float*)d_out;

  // Workspace layout
  float* hw = (float*)d_ws;                 // NN*MF floats
  int* offs = (int*)(hw + (size_t)NN * MF); // NN+1 (+3 pad)
  int* cnt = offs + NN + 4;                 // NN (counts -> local excl scan)
  int* cursor = cnt + NN;                   // NN
  int* eidx = cursor + NN;                  // NE
  int* bsum = eidx + NE;                    // 64
  int* base = bsum + 64;                    // 64
  const size_t need = ((size_t)NN * MF + (NN + 4) + NN + NN + NE + 128) * 4;
  if (ws_size < need) return;

  hipMemsetAsync(cnt, 0, (size_t)NN * sizeof(int), stream);

  gemm_mfma<<<(NN + 63) / 64, 256, 0, stream>>>(h, W, norm, hw);  // 782 blocks
  count_edges<<<(NE + 255) / 256, 256, 0, stream>>>(dst, cnt);
  scan_local<<<NBLK, SB, 0, stream>>>(cnt, bsum);
  scan_base<<<1, 64, 0, stream>>>(bsum, base);
  add_base<<<NBLK, SB, 0, stream>>>(cnt, base, offs, cursor);
  fill_edges<<<(NE + 255) / 256, 256, 0, stream>>>(src, dst, cursor, eidx);
  gather_finalize<<<(NN + 3) / 4, 256, 0, stream>>>(offs, eidx, hw, norm, bias, out);
}